// Round 6
// baseline (591.288 us; speedup 1.0000x reference)
//
#include <hip/hip_runtime.h>
#include <cstdint>

// ---------------------------------------------------------------------------
// Round 19. r18 (225.8 µs) analysis: gemm staging runs at 12.2 B/cy/CU ==
// the per-CU vector-load throughput wall (m13: 10.2). It is traffic-bound,
// not schedule-bound. Lever = bytes/FLOP with TLP >= ~3 gangs/CU.
// (1) gemm: 128x256 tile, BK=64, 512 thr, SINGLE 48KB buffer, drain-to-0
//     (r18's proven schedule). Traffic 442 -> 226 MB per gemm. 3 blocks/CU
//     (LDS 160/48), VGPR ~60 -> 6 waves/SIMD. gemm2 splitK=4 (576 blocks).
//     r15's failure was the 96KB dbuf -> 1 block/CU, NOT the tile.
// (2) dispatches 5 -> 4: assign+gather fused into scatter_k (wave per
//     assignment: atomic slot + direct x->Xg bf16 copy); pre_k absorbs
//     Xg/rowmap/rowgate/cursor init.
// Predict: gemm 59 -> 35-45 each, FETCH ~29MB, conflicts 0, total ~170-190.
// Fail-mode: gemm >= 75 -> revert tile, keep scatter.
// ---------------------------------------------------------------------------

#define T_TOK 4096
#define D_DIM 512
#define F_DIM 2048
#define E_EXP 8
#define NROWS 9216      // 8192 assignments + 8*128 pad
#define MAXTILES 72     // NROWS / 128

typedef __bf16 bf16x8 __attribute__((ext_vector_type(8)));
typedef float  f32x4  __attribute__((ext_vector_type(4)));
typedef unsigned short u16;
typedef unsigned short u16x8 __attribute__((ext_vector_type(8)));

__device__ __forceinline__ u16 f2b(float f) {
    return __builtin_bit_cast(unsigned short, (__bf16)f);
}
__device__ __forceinline__ void gload16(void* lds, const void* g) {
    __builtin_amdgcn_global_load_lds(
        (const __attribute__((address_space(1))) void*)g,
        (__attribute__((address_space(3))) void*)lds, 16, 0, 0);
}
// tanh-approx GELU (err ~3e-4 << bf16 ulp)
__device__ __forceinline__ float gelu_f(float v) {
    float z = 0.7978845608f * (v + 0.044715f * v * v * v);
    float t = 1.0f - 2.0f / (1.0f + __expf(2.0f * z));
    return 0.5f * v * (1.0f + t);
}

// ---------------- transpose tile body (shared by pre_k) ---------------------
__device__ __forceinline__ void tbody(const float* __restrict__ in,
                                      u16* __restrict__ out, int R, int C,
                                      int c0, int r0, int tid,
                                      float (*t)[65]) {
    int cq = tid & 15, rb = tid >> 4;
#pragma unroll
    for (int pass = 0; pass < 4; ++pass) {
        int rr = rb + pass * 16;
        float4 v = *(const float4*)(in + (size_t)(r0 + rr) * C + c0 + cq * 4);
        t[rr][cq * 4 + 0] = v.x; t[rr][cq * 4 + 1] = v.y;
        t[rr][cq * 4 + 2] = v.z; t[rr][cq * 4 + 3] = v.w;
    }
    __syncthreads();
    int rg = tid & 15, cb = tid >> 4;
#pragma unroll
    for (int pass = 0; pass < 4; ++pass) {
        int c = cb + pass * 16;
        ushort4 o;
        o.x = f2b(t[rg * 4 + 0][c]); o.y = f2b(t[rg * 4 + 1][c]);
        o.z = f2b(t[rg * 4 + 2][c]); o.w = f2b(t[rg * 4 + 3][c]);
        *(ushort4*)(out + (size_t)(c0 + c) * R + r0 + rg * 4) = o;
    }
}

// ---------------- pre_k: routing + transposes + all zero/init, ONE dispatch -
// [0,64): routing   [64,4160): W1/W2 transpose   [4160,5184): zero outm
// [5184,7488): zero Xg   [7488]: rowmap=-1, rowgate=0, cur=0
#define RT_BLKS 64
#define TR_BLKS 4096
#define ZO_BLKS 1024
#define XZ_BLKS 2304
#define PRE_BLOCKS (RT_BLKS + TR_BLKS + ZO_BLKS + XZ_BLKS + 1)

__global__ void pre_k(const float* __restrict__ x, const float* __restrict__ anchors,
                      const float* __restrict__ W1, u16* __restrict__ W1T,
                      const float* __restrict__ W2, u16* __restrict__ W2T,
                      float* __restrict__ outm, float* __restrict__ dout_an,
                      float* __restrict__ dout_scores, float* __restrict__ dout_idx,
                      int* __restrict__ idxs, float* __restrict__ gates,
                      int* __restrict__ cnthist, u16* __restrict__ Xg,
                      int* __restrict__ rowmap, float* __restrict__ rowgate,
                      int* __restrict__ cur) {
    __shared__ float shpool[E_EXP * 544];   // routing: anl; transpose: 64x65
    __shared__ int hist[E_EXP];
    int b = blockIdx.x;
    int tid = threadIdx.x;

    if (b >= RT_BLKS + TR_BLKS + ZO_BLKS + XZ_BLKS) {   // ---- misc init ----
        if (tid < E_EXP) cur[tid] = 0;
        for (int r = tid; r < NROWS; r += 256) {
            rowmap[r] = -1; rowgate[r] = 0.f;
        }
        return;
    }
    if (b >= RT_BLKS + TR_BLKS + ZO_BLKS) {             // ---- zero Xg ----
        int zb = b - (RT_BLKS + TR_BLKS + ZO_BLKS);
        float4* g4 = (float4*)Xg;
        g4[zb * 256 + tid] = float4{0.f, 0.f, 0.f, 0.f};
        return;
    }
    if (b >= RT_BLKS + TR_BLKS) {                       // ---- zero outm ----
        int zb = b - (RT_BLKS + TR_BLKS);
        float4* o4 = (float4*)outm;
        int i = zb * 256 + tid;
        o4[i] = float4{0.f, 0.f, 0.f, 0.f};
        o4[i + ZO_BLKS * 256] = float4{0.f, 0.f, 0.f, 0.f};
        return;
    }
    if (b >= RT_BLKS) {                                 // ---- transposes ----
        float (*tsh)[65] = (float(*)[65])shpool;        // 4160 floats <= 4352
        int tt = b - RT_BLKS;
        if (tt < 2048) {                    // W1 [E][512][2048] -> [E][2048][512]
            int bx = tt & 31, by = (tt >> 5) & 7, bz = tt >> 8;
            size_t zoff = (size_t)bz * D_DIM * F_DIM;
            tbody(W1 + zoff, W1T + zoff, D_DIM, F_DIM, bx * 64, by * 64, tid, tsh);
        } else {                            // W2 [E][2048][512] -> [E][512][2048]
            int t2 = tt - 2048;
            int bx = t2 & 7, by = (t2 >> 3) & 31, bz = t2 >> 8;
            size_t zoff = (size_t)bz * D_DIM * F_DIM;
            tbody(W2 + zoff, W2T + zoff, F_DIM, D_DIM, bx * 64, by * 64, tid, tsh);
        }
        return;
    }

    // ---- routing ----
    float* anl = shpool;                    // [e][p*136 + i], i<128
    if (tid < E_EXP) hist[tid] = 0;
    for (int i = tid; i < E_EXP * D_DIM; i += 256) {
        int e = i >> 9, d = i & 511;
        anl[e * 544 + (d >> 7) * 136 + (d & 127)] = anchors[i];
    }
    __syncthreads();
    {   // normalize anchors in LDS: 32 threads per anchor
        int e = tid >> 5, l = tid & 31;
        float ss = 0.f;
        for (int d = l; d < D_DIM; d += 32) {
            float v = anl[e * 544 + (d >> 7) * 136 + (d & 127)];
            ss += v * v;
        }
#pragma unroll
        for (int off = 16; off >= 1; off >>= 1) ss += __shfl_xor(ss, off, 32);
        float inv = 1.0f / fmaxf(sqrtf(ss), 1e-8f);
        for (int d = l; d < D_DIM; d += 32) {
            int ix = e * 544 + (d >> 7) * 136 + (d & 127);
            float nv = anl[ix] * inv;
            anl[ix] = nv;
            if (b == 0) dout_an[e * D_DIM + d] = nv;
        }
    }
    __syncthreads();

    int p = tid & 3;
    int tok = b * 64 + (tid >> 2);
    const float4* xr = (const float4*)(x + (size_t)tok * D_DIM + p * 128);
    const float* ab = &anl[p * 136];
    float dot[E_EXP] = {};
    float ss = 0.f;
    for (int c = 0; c < 32; ++c) {
        float4 xv = xr[c];
        ss += xv.x*xv.x + xv.y*xv.y + xv.z*xv.z + xv.w*xv.w;
#pragma unroll
        for (int e = 0; e < E_EXP; ++e) {
            float4 av = *(const float4*)&ab[e * 544 + c * 4];
            dot[e] += xv.x*av.x + xv.y*av.y + xv.z*av.z + xv.w*av.w;
        }
    }
#pragma unroll
    for (int off = 1; off <= 2; off <<= 1) {
        ss += __shfl_xor(ss, off, 64);
#pragma unroll
        for (int e = 0; e < E_EXP; ++e) dot[e] += __shfl_xor(dot[e], off, 64);
    }

    if (p == 0) {
        float inv = 1.0f / fmaxf(sqrtf(ss), 1e-8f);
        float s[E_EXP];
#pragma unroll
        for (int e = 0; e < E_EXP; ++e) s[e] = dot[e] * inv;
        int i0 = 0; float b0 = s[0];
#pragma unroll
        for (int e = 1; e < E_EXP; ++e) if (s[e] > b0) { b0 = s[e]; i0 = e; }
        int i1 = -1; float b1v = -1e30f;
#pragma unroll
        for (int e = 0; e < E_EXP; ++e)
            if (e != i0 && s[e] > b1v) { b1v = s[e]; i1 = e; }
        if (i1 < 0) { i1 = (i0 + 1) & 7; b1v = s[i1]; }   // NaN-safety
        float g0 = 1.0f / (1.0f + expf(b1v - b0));
        float g1 = 1.0f - g0;
#pragma unroll
        for (int e = 0; e < E_EXP; ++e) dout_scores[tok * E_EXP + e] = s[e];
        dout_idx[tok * 2 + 0] = (float)i0;
        dout_idx[tok * 2 + 1] = (float)i1;
        idxs[tok * 2 + 0] = i0; idxs[tok * 2 + 1] = i1;
        gates[tok * 2 + 0] = g0; gates[tok * 2 + 1] = g1;
        atomicAdd(&hist[i0], 1);
        atomicAdd(&hist[i1], 1);
    }
    __syncthreads();
    if (tid < E_EXP) cnthist[b * E_EXP + tid] = hist[tid];
}

// ---------------- scatter_k: fused assign + gather (wave per assignment) ----
// 2048 blocks x 256 thr = 8192 waves? no: 4 waves/block -> 8192 pairs.
// Each wave: atomic slot grab in expert bucket, write rowmap/rowgate, copy
// x[t] row -> Xg[r] bf16 (64 lanes x 8 elems). Block 0 publishes offs.
__global__ void scatter_k(const float* __restrict__ x, const int* __restrict__ cnthist,
                          const int* __restrict__ idxs, const float* __restrict__ gates,
                          int* __restrict__ cur, int* __restrict__ offs,
                          int* __restrict__ rowmap, float* __restrict__ rowgate,
                          u16* __restrict__ Xg) {
    __shared__ int soff[E_EXP + 1];
    __shared__ int scnt[E_EXP];
    int tid = threadIdx.x;
    if (tid < E_EXP) {
        int s = 0;
        for (int b = 0; b < RT_BLKS; ++b) s += cnthist[b * E_EXP + tid];
        scnt[tid] = s;
    }
    __syncthreads();
    if (tid == 0) {
        int acc = 0;
        for (int e = 0; e < E_EXP; ++e) { soff[e] = acc; acc += (scnt[e] + 127) & ~127; }
        soff[E_EXP] = acc;
    }
    __syncthreads();
    if (blockIdx.x == 0 && tid <= E_EXP) offs[tid] = soff[tid];

    int w = tid >> 6, lane = tid & 63;
    int p = blockIdx.x * 4 + w;          // assignment pair 0..8191
    int t = p >> 1, k = p & 1;
    int e = idxs[t * 2 + k];
    e = min(max(e, 0), E_EXP - 1);
    int r = 0;
    if (lane == 0) r = soff[e] + atomicAdd(&cur[e], 1);
    r = __shfl(r, 0, 64);
    if (lane == 0) {
        rowmap[r] = t;
        rowgate[r] = gates[t * 2 + k];
    }
    const float4* xs = (const float4*)(x + (size_t)t * D_DIM + lane * 8);
    float4 v0 = xs[0], v1 = xs[1];
    u16x8 o = { f2b(v0.x), f2b(v0.y), f2b(v0.z), f2b(v0.w),
                f2b(v1.x), f2b(v1.y), f2b(v1.z), f2b(v1.w) };
    *(u16x8*)(Xg + (size_t)r * D_DIM + lane * 8) = o;
}

// ---------------- grouped GEMM core (r19: 128x256, single 48KB buf) ---------
// MODE 0: Hg = bf16(gelu(Xg @ W1e^T + b1e))         (N=F, K=D), nT=8
// MODE 1: out[tok] += gate*(Hg @ W2e^T + [z0]b2e)   (N=D, K=F, split-K=4), nT=2
// 512 thr = 8 waves (2m x 4n, 64x64/wave). Single-buffer drain-to-0 schedule
// (r18's proven one). 48KB LDS -> 3 blocks/CU; VGPR ~60 -> 6 waves/SIMD.
// Traffic halves vs 128^2: (128+256)*64*2B per step for 2x the MFMA.
// XOR col swizzle kc^(row&7): global source pre-swizzled, read side XORed.
#define ABUF (128 * 64)
#define BBUF (256 * 64)
template <int MODE>
__launch_bounds__(512, 6)
__global__ void gemm_k(const u16* __restrict__ A, int lda,
                       const u16* __restrict__ BtBase, int ldb,
                       u16* __restrict__ Hout, const float* __restrict__ b1,
                       float* __restrict__ outm, const float* __restrict__ b2,
                       const int* __restrict__ rowmap, const float* __restrict__ rowgate,
                       const int* __restrict__ offs, int kPer, int nT) {
    int L = blockIdx.x;
    int per = gridDim.x >> 3;
    int tile = (L & 7) * per + (L >> 3);
    int z = 0;
    if (MODE == 1) {                 // split-K 4: gridDim = 4 * (72*2)
        int nz = gridDim.x >> 2;
        z = tile / nz; tile -= z * nz;
    }
    int mtile = tile / nT;
    int n0 = (tile - mtile * nT) * 256;
    int row0 = mtile * 128;
    if (row0 >= offs[E_EXP]) return;
    int e = 0;
#pragma unroll
    for (int i = 1; i < E_EXP; ++i) if (row0 >= offs[i]) e = i;
    const u16* Bt = BtBase + (size_t)e * D_DIM * F_DIM;
    int k_begin = z * kPer;
    int k_end = k_begin + kPer;

    alignas(16) __shared__ u16 As[ABUF];
    alignas(16) __shared__ u16 Bs[BBUF];

    int tid = threadIdx.x;
    int lane = tid & 63;
    int wv = tid >> 6;               // 0..7
    int wm = wv & 1;                 // 2 M-halves (64 rows)
    int wn = wv >> 1;                // 4 N-quarters (64 cols)
    int kq = lane >> 4;              // quad 0..3
    int l15 = lane & 15;

    // staging: A = 2 x 512 slots, B = 4 x 512 slots; slot -> (m = slot>>3,
    // kc = slot&7). LDS dest LINEAR slot*16B; global col pre-swizzled.
    const u16* aS[2]; int aOff[2];
    const u16* bS[4]; int bOff[4];
#pragma unroll
    for (int i = 0; i < 2; ++i) {
        int slot = i * 512 + tid;
        int m = slot >> 3;
        int kcs = (slot & 7) ^ (m & 7);
        aS[i] = A + (size_t)(row0 + m) * lda + kcs * 8;
        aOff[i] = slot * 8;
    }
#pragma unroll
    for (int i = 0; i < 4; ++i) {
        int slot = i * 512 + tid;
        int m = slot >> 3;
        int kcs = (slot & 7) ^ (m & 7);
        bS[i] = Bt + (size_t)(n0 + m) * ldb + kcs * 8;
        bOff[i] = slot * 8;
    }

    f32x4 acc[4][4];
#pragma unroll
    for (int i = 0; i < 4; ++i)
#pragma unroll
        for (int j = 0; j < 4; ++j) acc[i][j] = f32x4{0.f, 0.f, 0.f, 0.f};

    int sx = l15 & 7;                // row&7 == l15&7
    for (int k0 = k_begin; k0 < k_end; k0 += 64) {
#pragma unroll
        for (int i = 0; i < 2; ++i) gload16(As + aOff[i], aS[i] + k0);
#pragma unroll
        for (int i = 0; i < 4; ++i) gload16(Bs + bOff[i], bS[i] + k0);
        asm volatile("s_waitcnt vmcnt(0)" ::: "memory");
        __syncthreads();
#pragma unroll
        for (int kk = 0; kk < 2; ++kk) {
            int kc = kk * 4 + kq;
            int kca = kc ^ sx;       // swizzled column on the read side
            bf16x8 af[4], bfr[4];
#pragma unroll
            for (int i = 0; i < 4; ++i) {
                int rowA = wm * 64 + i * 16 + l15;
                af[i] = *(const bf16x8*)(As + rowA * 64 + kca * 8);
                int rowB = wn * 64 + i * 16 + l15;
                bfr[i] = *(const bf16x8*)(Bs + rowB * 64 + kca * 8);
            }
#pragma unroll
            for (int i = 0; i < 4; ++i)
#pragma unroll
                for (int j = 0; j < 4; ++j)
                    acc[i][j] = __builtin_amdgcn_mfma_f32_16x16x32_bf16(
                        af[i], bfr[j], acc[i][j], 0, 0, 0);
        }
        __syncthreads();
    }

    if constexpr (MODE == 0) {
        const float* b1e = b1 + (size_t)e * F_DIM;
#pragma unroll
        for (int i = 0; i < 4; ++i) {
            int gr = row0 + wm * 64 + i * 16 + kq * 4;
#pragma unroll
            for (int j = 0; j < 4; ++j) {
                int gc = n0 + wn * 64 + j * 16 + l15;
                float bb = b1e[gc];
#pragma unroll
                for (int r = 0; r < 4; ++r) {
                    float v = acc[i][j][r] + bb;
                    Hout[(size_t)(gr + r) * F_DIM + gc] = f2b(gelu_f(v));
                }
            }
        }
    } else {
        const float* b2e = b2 + (size_t)e * D_DIM;
        bool addBias = (k_begin == 0);
#pragma unroll
        for (int i = 0; i < 4; ++i) {
            int grb = row0 + wm * 64 + i * 16 + kq * 4;
#pragma unroll
            for (int r = 0; r < 4; ++r) {
                int tok = rowmap[grb + r];
                float g = rowgate[grb + r];
                if (tok >= 0 && tok < T_TOK) {
                    float* orow = outm + (size_t)tok * D_DIM;
#pragma unroll
                    for (int j = 0; j < 4; ++j) {
                        int gc = n0 + wn * 64 + j * 16 + l15;
                        float bb = addBias ? b2e[gc] : 0.f;
                        atomicAdd(orow + gc, g * (acc[i][j][r] + bb));
                    }
                }
            }
        }
    }
}

// ---------------- workspace layout (bytes) ----------------------------------
#define OFF_CNTH    0x10000u     // int[64*8] per-block histograms
#define OFF_OFFS    0x10900u     // int[9]
#define OFF_CUR     0x10A00u     // int[8] atomic cursors
#define OFF_IDX     0x20000u     // int[T*2]
#define OFF_GATE    0x28000u     // float[T*2]
#define OFF_ROWMAP  0x30000u     // int[NROWS]
#define OFF_ROWGATE 0x40000u     // float[NROWS]
#define OFF_XG      0x900000u    // 9.44 MB u16[NROWS*D]  -> ends 0x1200000
#define OFF_W1T     0x1200000u   // 16.78 MB u16[E][F][D] -> ends 0x2200000
#define OFF_W2T     0x2200000u   // 16.78 MB u16[E][D][F] -> ends 0x3200000
#define OFF_HG      0x3200000u   // 37.75 MB u16[NROWS*F] -> ends 0x5600000

extern "C" void kernel_launch(void* const* d_in, const int* in_sizes, int n_in,
                              void* d_out, int out_size, void* d_ws, size_t ws_size,
                              hipStream_t stream) {
    const float* x       = (const float*)d_in[0];
    const float* anchors = (const float*)d_in[1];
    const float* W1      = (const float*)d_in[2];
    const float* b1      = (const float*)d_in[3];
    const float* W2      = (const float*)d_in[4];
    const float* b2      = (const float*)d_in[5];
    float* out = (float*)d_out;

    char* ws = (char*)d_ws;
    int*   cnthist = (int*)(ws + OFF_CNTH);
    int*   offs    = (int*)(ws + OFF_OFFS);
    int*   cur     = (int*)(ws + OFF_CUR);
    int*   idxs    = (int*)(ws + OFF_IDX);
    float* gates   = (float*)(ws + OFF_GATE);
    int*   rowmap  = (int*)(ws + OFF_ROWMAP);
    float* rowgate = (float*)(ws + OFF_ROWGATE);
    u16*   Xg      = (u16*)(ws + OFF_XG);
    u16*   W1T     = (u16*)(ws + OFF_W1T);
    u16*   W2T     = (u16*)(ws + OFF_W2T);
    u16*   Hg      = (u16*)(ws + OFF_HG);

    // d_out sections (fp32 elements): out | a_n | scores | topk_idx
    float* out_main   = out;
    float* out_an     = out + (size_t)T_TOK * D_DIM;
    float* out_scores = out_an + E_EXP * D_DIM;
    float* out_idx    = out_scores + (size_t)T_TOK * E_EXP;

    pre_k<<<PRE_BLOCKS, 256, 0, stream>>>(x, anchors, W1, W1T, W2, W2T,
                                          out_main, out_an, out_scores, out_idx,
                                          idxs, gates, cnthist, Xg,
                                          rowmap, rowgate, cur);
    scatter_k<<<2048, 256, 0, stream>>>(x, cnthist, idxs, gates, cur, offs,
                                        rowmap, rowgate, Xg);
    // gemm1: 8 n-tiles(256) x 72 m-tiles(128) = 576 blocks (XCD-swizzled)
    gemm_k<0><<<8 * MAXTILES, 512, 0, stream>>>(
        Xg, D_DIM, W1T, D_DIM, Hg, b1, nullptr, nullptr,
        rowmap, nullptr, offs, D_DIM, 8);
    // gemm2: 2 n-tiles(256) x 72 m-tiles x splitK4 = 576 blocks
    gemm_k<1><<<2 * MAXTILES * 4, 512, 0, stream>>>(
        Hg, F_DIM, W2T, F_DIM, nullptr, nullptr, out_main, b2,
        rowmap, rowgate, offs, F_DIM / 4, 2);
}

// Round 7
// 364.103 us; speedup vs baseline: 1.6240x; 1.6240x over previous
//
#include <hip/hip_runtime.h>
#include <cstdint>

// ---------------------------------------------------------------------------
// Round 20. r19 post-mortem: 591 µs regression was launch_bounds(512,6)
// forcing 24 waves/CU -> ~85-reg budget < 124 needed (64 AGPR acc + ~60
// VGPR) -> accumulator SPILLED to scratch (VGPR 60->40, FETCH 29->270MB,
// WRITE 33->543MB). The 128x256 tile was never actually tested. Single fix:
// launch_bounds(512,4) -> 128-reg target, body fits (124), 16 waves/CU =
// 2 blocks x 8 waves = same TLP as r18 with 75% of the staged bytes/FLOP.
// Predict: VGPR ~60, WRITE back to 33MB, FETCH 29MB, gemm 45-55 us each,
// total 195-215. If gemm ~59 -> issue-bound not byte-bound -> revert tile.
// ---------------------------------------------------------------------------

#define T_TOK 4096
#define D_DIM 512
#define F_DIM 2048
#define E_EXP 8
#define NROWS 9216      // 8192 assignments + 8*128 pad
#define MAXTILES 72     // NROWS / 128

typedef __bf16 bf16x8 __attribute__((ext_vector_type(8)));
typedef float  f32x4  __attribute__((ext_vector_type(4)));
typedef unsigned short u16;
typedef unsigned short u16x8 __attribute__((ext_vector_type(8)));

__device__ __forceinline__ u16 f2b(float f) {
    return __builtin_bit_cast(unsigned short, (__bf16)f);
}
__device__ __forceinline__ void gload16(void* lds, const void* g) {
    __builtin_amdgcn_global_load_lds(
        (const __attribute__((address_space(1))) void*)g,
        (__attribute__((address_space(3))) void*)lds, 16, 0, 0);
}
// tanh-approx GELU (err ~3e-4 << bf16 ulp)
__device__ __forceinline__ float gelu_f(float v) {
    float z = 0.7978845608f * (v + 0.044715f * v * v * v);
    float t = 1.0f - 2.0f / (1.0f + __expf(2.0f * z));
    return 0.5f * v * (1.0f + t);
}

// ---------------- transpose tile body (shared by pre_k) ---------------------
__device__ __forceinline__ void tbody(const float* __restrict__ in,
                                      u16* __restrict__ out, int R, int C,
                                      int c0, int r0, int tid,
                                      float (*t)[65]) {
    int cq = tid & 15, rb = tid >> 4;
#pragma unroll
    for (int pass = 0; pass < 4; ++pass) {
        int rr = rb + pass * 16;
        float4 v = *(const float4*)(in + (size_t)(r0 + rr) * C + c0 + cq * 4);
        t[rr][cq * 4 + 0] = v.x; t[rr][cq * 4 + 1] = v.y;
        t[rr][cq * 4 + 2] = v.z; t[rr][cq * 4 + 3] = v.w;
    }
    __syncthreads();
    int rg = tid & 15, cb = tid >> 4;
#pragma unroll
    for (int pass = 0; pass < 4; ++pass) {
        int c = cb + pass * 16;
        ushort4 o;
        o.x = f2b(t[rg * 4 + 0][c]); o.y = f2b(t[rg * 4 + 1][c]);
        o.z = f2b(t[rg * 4 + 2][c]); o.w = f2b(t[rg * 4 + 3][c]);
        *(ushort4*)(out + (size_t)(c0 + c) * R + r0 + rg * 4) = o;
    }
}

// ---------------- pre_k: routing + transposes + all zero/init, ONE dispatch -
// [0,64): routing   [64,4160): W1/W2 transpose   [4160,5184): zero outm
// [5184,7488): zero Xg   [7488]: rowmap=-1, rowgate=0, cur=0
#define RT_BLKS 64
#define TR_BLKS 4096
#define ZO_BLKS 1024
#define XZ_BLKS 2304
#define PRE_BLOCKS (RT_BLKS + TR_BLKS + ZO_BLKS + XZ_BLKS + 1)

__global__ void pre_k(const float* __restrict__ x, const float* __restrict__ anchors,
                      const float* __restrict__ W1, u16* __restrict__ W1T,
                      const float* __restrict__ W2, u16* __restrict__ W2T,
                      float* __restrict__ outm, float* __restrict__ dout_an,
                      float* __restrict__ dout_scores, float* __restrict__ dout_idx,
                      int* __restrict__ idxs, float* __restrict__ gates,
                      int* __restrict__ cnthist, u16* __restrict__ Xg,
                      int* __restrict__ rowmap, float* __restrict__ rowgate,
                      int* __restrict__ cur) {
    __shared__ float shpool[E_EXP * 544];   // routing: anl; transpose: 64x65
    __shared__ int hist[E_EXP];
    int b = blockIdx.x;
    int tid = threadIdx.x;

    if (b >= RT_BLKS + TR_BLKS + ZO_BLKS + XZ_BLKS) {   // ---- misc init ----
        if (tid < E_EXP) cur[tid] = 0;
        for (int r = tid; r < NROWS; r += 256) {
            rowmap[r] = -1; rowgate[r] = 0.f;
        }
        return;
    }
    if (b >= RT_BLKS + TR_BLKS + ZO_BLKS) {             // ---- zero Xg ----
        int zb = b - (RT_BLKS + TR_BLKS + ZO_BLKS);
        float4* g4 = (float4*)Xg;
        g4[zb * 256 + tid] = float4{0.f, 0.f, 0.f, 0.f};
        return;
    }
    if (b >= RT_BLKS + TR_BLKS) {                       // ---- zero outm ----
        int zb = b - (RT_BLKS + TR_BLKS);
        float4* o4 = (float4*)outm;
        int i = zb * 256 + tid;
        o4[i] = float4{0.f, 0.f, 0.f, 0.f};
        o4[i + ZO_BLKS * 256] = float4{0.f, 0.f, 0.f, 0.f};
        return;
    }
    if (b >= RT_BLKS) {                                 // ---- transposes ----
        float (*tsh)[65] = (float(*)[65])shpool;        // 4160 floats <= 4352
        int tt = b - RT_BLKS;
        if (tt < 2048) {                    // W1 [E][512][2048] -> [E][2048][512]
            int bx = tt & 31, by = (tt >> 5) & 7, bz = tt >> 8;
            size_t zoff = (size_t)bz * D_DIM * F_DIM;
            tbody(W1 + zoff, W1T + zoff, D_DIM, F_DIM, bx * 64, by * 64, tid, tsh);
        } else {                            // W2 [E][2048][512] -> [E][512][2048]
            int t2 = tt - 2048;
            int bx = t2 & 7, by = (t2 >> 3) & 31, bz = t2 >> 8;
            size_t zoff = (size_t)bz * D_DIM * F_DIM;
            tbody(W2 + zoff, W2T + zoff, F_DIM, D_DIM, bx * 64, by * 64, tid, tsh);
        }
        return;
    }

    // ---- routing ----
    float* anl = shpool;                    // [e][p*136 + i], i<128
    if (tid < E_EXP) hist[tid] = 0;
    for (int i = tid; i < E_EXP * D_DIM; i += 256) {
        int e = i >> 9, d = i & 511;
        anl[e * 544 + (d >> 7) * 136 + (d & 127)] = anchors[i];
    }
    __syncthreads();
    {   // normalize anchors in LDS: 32 threads per anchor
        int e = tid >> 5, l = tid & 31;
        float ss = 0.f;
        for (int d = l; d < D_DIM; d += 32) {
            float v = anl[e * 544 + (d >> 7) * 136 + (d & 127)];
            ss += v * v;
        }
#pragma unroll
        for (int off = 16; off >= 1; off >>= 1) ss += __shfl_xor(ss, off, 32);
        float inv = 1.0f / fmaxf(sqrtf(ss), 1e-8f);
        for (int d = l; d < D_DIM; d += 32) {
            int ix = e * 544 + (d >> 7) * 136 + (d & 127);
            float nv = anl[ix] * inv;
            anl[ix] = nv;
            if (b == 0) dout_an[e * D_DIM + d] = nv;
        }
    }
    __syncthreads();

    int p = tid & 3;
    int tok = b * 64 + (tid >> 2);
    const float4* xr = (const float4*)(x + (size_t)tok * D_DIM + p * 128);
    const float* ab = &anl[p * 136];
    float dot[E_EXP] = {};
    float ss = 0.f;
    for (int c = 0; c < 32; ++c) {
        float4 xv = xr[c];
        ss += xv.x*xv.x + xv.y*xv.y + xv.z*xv.z + xv.w*xv.w;
#pragma unroll
        for (int e = 0; e < E_EXP; ++e) {
            float4 av = *(const float4*)&ab[e * 544 + c * 4];
            dot[e] += xv.x*av.x + xv.y*av.y + xv.z*av.z + xv.w*av.w;
        }
    }
#pragma unroll
    for (int off = 1; off <= 2; off <<= 1) {
        ss += __shfl_xor(ss, off, 64);
#pragma unroll
        for (int e = 0; e < E_EXP; ++e) dot[e] += __shfl_xor(dot[e], off, 64);
    }

    if (p == 0) {
        float inv = 1.0f / fmaxf(sqrtf(ss), 1e-8f);
        float s[E_EXP];
#pragma unroll
        for (int e = 0; e < E_EXP; ++e) s[e] = dot[e] * inv;
        int i0 = 0; float b0 = s[0];
#pragma unroll
        for (int e = 1; e < E_EXP; ++e) if (s[e] > b0) { b0 = s[e]; i0 = e; }
        int i1 = -1; float b1v = -1e30f;
#pragma unroll
        for (int e = 0; e < E_EXP; ++e)
            if (e != i0 && s[e] > b1v) { b1v = s[e]; i1 = e; }
        if (i1 < 0) { i1 = (i0 + 1) & 7; b1v = s[i1]; }   // NaN-safety
        float g0 = 1.0f / (1.0f + expf(b1v - b0));
        float g1 = 1.0f - g0;
#pragma unroll
        for (int e = 0; e < E_EXP; ++e) dout_scores[tok * E_EXP + e] = s[e];
        dout_idx[tok * 2 + 0] = (float)i0;
        dout_idx[tok * 2 + 1] = (float)i1;
        idxs[tok * 2 + 0] = i0; idxs[tok * 2 + 1] = i1;
        gates[tok * 2 + 0] = g0; gates[tok * 2 + 1] = g1;
        atomicAdd(&hist[i0], 1);
        atomicAdd(&hist[i1], 1);
    }
    __syncthreads();
    if (tid < E_EXP) cnthist[b * E_EXP + tid] = hist[tid];
}

// ---------------- scatter_k: fused assign + gather (wave per assignment) ----
// 2048 blocks x 4 waves = 8192 waves = one per (token,k) assignment.
// Each wave: atomic slot grab in expert bucket, write rowmap/rowgate, copy
// x[t] row -> Xg[r] bf16 (64 lanes x 8 elems). Block 0 publishes offs.
__global__ void scatter_k(const float* __restrict__ x, const int* __restrict__ cnthist,
                          const int* __restrict__ idxs, const float* __restrict__ gates,
                          int* __restrict__ cur, int* __restrict__ offs,
                          int* __restrict__ rowmap, float* __restrict__ rowgate,
                          u16* __restrict__ Xg) {
    __shared__ int soff[E_EXP + 1];
    __shared__ int scnt[E_EXP];
    int tid = threadIdx.x;
    if (tid < E_EXP) {
        int s = 0;
        for (int b = 0; b < RT_BLKS; ++b) s += cnthist[b * E_EXP + tid];
        scnt[tid] = s;
    }
    __syncthreads();
    if (tid == 0) {
        int acc = 0;
        for (int e = 0; e < E_EXP; ++e) { soff[e] = acc; acc += (scnt[e] + 127) & ~127; }
        soff[E_EXP] = acc;
    }
    __syncthreads();
    if (blockIdx.x == 0 && tid <= E_EXP) offs[tid] = soff[tid];

    int w = tid >> 6, lane = tid & 63;
    int p = blockIdx.x * 4 + w;          // assignment pair 0..8191
    int t = p >> 1, k = p & 1;
    int e = idxs[t * 2 + k];
    e = min(max(e, 0), E_EXP - 1);
    int r = 0;
    if (lane == 0) r = soff[e] + atomicAdd(&cur[e], 1);
    r = __shfl(r, 0, 64);
    if (lane == 0) {
        rowmap[r] = t;
        rowgate[r] = gates[t * 2 + k];
    }
    const float4* xs = (const float4*)(x + (size_t)t * D_DIM + lane * 8);
    float4 v0 = xs[0], v1 = xs[1];
    u16x8 o = { f2b(v0.x), f2b(v0.y), f2b(v0.z), f2b(v0.w),
                f2b(v1.x), f2b(v1.y), f2b(v1.z), f2b(v1.w) };
    *(u16x8*)(Xg + (size_t)r * D_DIM + lane * 8) = o;
}

// ---------------- grouped GEMM core (r20: 128x256, single 48KB buf) ---------
// MODE 0: Hg = bf16(gelu(Xg @ W1e^T + b1e))         (N=F, K=D), nT=8
// MODE 1: out[tok] += gate*(Hg @ W2e^T + [z0]b2e)   (N=D, K=F, split-K=4), nT=2
// 512 thr = 8 waves (2m x 4n, 64x64/wave). Single-buffer drain-to-0 schedule
// (r18's proven one). Regs: 64 AGPR acc + ~60 VGPR = 124 combined -> fits
// 4 waves/SIMD (<=128) -> 2 blocks x 8 waves = 16 waves/CU (same TLP as r18)
// with 75% of r18's staged bytes/FLOP. launch_bounds(512,4) targets exactly
// that; (512,6) was the r19 spill disaster.
// XOR col swizzle kc^(row&7): global source pre-swizzled, read side XORed.
#define ABUF (128 * 64)
#define BBUF (256 * 64)
template <int MODE>
__launch_bounds__(512, 4)
__global__ void gemm_k(const u16* __restrict__ A, int lda,
                       const u16* __restrict__ BtBase, int ldb,
                       u16* __restrict__ Hout, const float* __restrict__ b1,
                       float* __restrict__ outm, const float* __restrict__ b2,
                       const int* __restrict__ rowmap, const float* __restrict__ rowgate,
                       const int* __restrict__ offs, int kPer, int nT) {
    int L = blockIdx.x;
    int per = gridDim.x >> 3;
    int tile = (L & 7) * per + (L >> 3);
    int z = 0;
    if (MODE == 1) {                 // split-K 4: gridDim = 4 * (72*2)
        int nz = gridDim.x >> 2;
        z = tile / nz; tile -= z * nz;
    }
    int mtile = tile / nT;
    int n0 = (tile - mtile * nT) * 256;
    int row0 = mtile * 128;
    if (row0 >= offs[E_EXP]) return;
    int e = 0;
#pragma unroll
    for (int i = 1; i < E_EXP; ++i) if (row0 >= offs[i]) e = i;
    const u16* Bt = BtBase + (size_t)e * D_DIM * F_DIM;
    int k_begin = z * kPer;
    int k_end = k_begin + kPer;

    alignas(16) __shared__ u16 As[ABUF];
    alignas(16) __shared__ u16 Bs[BBUF];

    int tid = threadIdx.x;
    int lane = tid & 63;
    int wv = tid >> 6;               // 0..7
    int wm = wv & 1;                 // 2 M-halves (64 rows)
    int wn = wv >> 1;                // 4 N-quarters (64 cols)
    int kq = lane >> 4;              // quad 0..3
    int l15 = lane & 15;

    // staging: A = 2 x 512 slots, B = 4 x 512 slots; slot -> (m = slot>>3,
    // kc = slot&7). LDS dest LINEAR slot*16B; global col pre-swizzled.
    const u16* aS[2]; int aOff[2];
    const u16* bS[4]; int bOff[4];
#pragma unroll
    for (int i = 0; i < 2; ++i) {
        int slot = i * 512 + tid;
        int m = slot >> 3;
        int kcs = (slot & 7) ^ (m & 7);
        aS[i] = A + (size_t)(row0 + m) * lda + kcs * 8;
        aOff[i] = slot * 8;
    }
#pragma unroll
    for (int i = 0; i < 4; ++i) {
        int slot = i * 512 + tid;
        int m = slot >> 3;
        int kcs = (slot & 7) ^ (m & 7);
        bS[i] = Bt + (size_t)(n0 + m) * ldb + kcs * 8;
        bOff[i] = slot * 8;
    }

    f32x4 acc[4][4];
#pragma unroll
    for (int i = 0; i < 4; ++i)
#pragma unroll
        for (int j = 0; j < 4; ++j) acc[i][j] = f32x4{0.f, 0.f, 0.f, 0.f};

    int sx = l15 & 7;                // row&7 == l15&7
    for (int k0 = k_begin; k0 < k_end; k0 += 64) {
#pragma unroll
        for (int i = 0; i < 2; ++i) gload16(As + aOff[i], aS[i] + k0);
#pragma unroll
        for (int i = 0; i < 4; ++i) gload16(Bs + bOff[i], bS[i] + k0);
        asm volatile("s_waitcnt vmcnt(0)" ::: "memory");
        __syncthreads();
#pragma unroll
        for (int kk = 0; kk < 2; ++kk) {
            int kc = kk * 4 + kq;
            int kca = kc ^ sx;       // swizzled column on the read side
            bf16x8 af[4], bfr[4];
#pragma unroll
            for (int i = 0; i < 4; ++i) {
                int rowA = wm * 64 + i * 16 + l15;
                af[i] = *(const bf16x8*)(As + rowA * 64 + kca * 8);
                int rowB = wn * 64 + i * 16 + l15;
                bfr[i] = *(const bf16x8*)(Bs + rowB * 64 + kca * 8);
            }
#pragma unroll
            for (int i = 0; i < 4; ++i)
#pragma unroll
                for (int j = 0; j < 4; ++j)
                    acc[i][j] = __builtin_amdgcn_mfma_f32_16x16x32_bf16(
                        af[i], bfr[j], acc[i][j], 0, 0, 0);
        }
        __syncthreads();
    }

    if constexpr (MODE == 0) {
        const float* b1e = b1 + (size_t)e * F_DIM;
#pragma unroll
        for (int i = 0; i < 4; ++i) {
            int gr = row0 + wm * 64 + i * 16 + kq * 4;
#pragma unroll
            for (int j = 0; j < 4; ++j) {
                int gc = n0 + wn * 64 + j * 16 + l15;
                float bb = b1e[gc];
#pragma unroll
                for (int r = 0; r < 4; ++r) {
                    float v = acc[i][j][r] + bb;
                    Hout[(size_t)(gr + r) * F_DIM + gc] = f2b(gelu_f(v));
                }
            }
        }
    } else {
        const float* b2e = b2 + (size_t)e * D_DIM;
        bool addBias = (k_begin == 0);
#pragma unroll
        for (int i = 0; i < 4; ++i) {
            int grb = row0 + wm * 64 + i * 16 + kq * 4;
#pragma unroll
            for (int r = 0; r < 4; ++r) {
                int tok = rowmap[grb + r];
                float g = rowgate[grb + r];
                if (tok >= 0 && tok < T_TOK) {
                    float* orow = outm + (size_t)tok * D_DIM;
#pragma unroll
                    for (int j = 0; j < 4; ++j) {
                        int gc = n0 + wn * 64 + j * 16 + l15;
                        float bb = addBias ? b2e[gc] : 0.f;
                        atomicAdd(orow + gc, g * (acc[i][j][r] + bb));
                    }
                }
            }
        }
    }
}

// ---------------- workspace layout (bytes) ----------------------------------
#define OFF_CNTH    0x10000u     // int[64*8] per-block histograms
#define OFF_OFFS    0x10900u     // int[9]
#define OFF_CUR     0x10A00u     // int[8] atomic cursors
#define OFF_IDX     0x20000u     // int[T*2]
#define OFF_GATE    0x28000u     // float[T*2]
#define OFF_ROWMAP  0x30000u     // int[NROWS]
#define OFF_ROWGATE 0x40000u     // float[NROWS]
#define OFF_XG      0x900000u    // 9.44 MB u16[NROWS*D]  -> ends 0x1200000
#define OFF_W1T     0x1200000u   // 16.78 MB u16[E][F][D] -> ends 0x2200000
#define OFF_W2T     0x2200000u   // 16.78 MB u16[E][D][F] -> ends 0x3200000
#define OFF_HG      0x3200000u   // 37.75 MB u16[NROWS*F] -> ends 0x5600000

extern "C" void kernel_launch(void* const* d_in, const int* in_sizes, int n_in,
                              void* d_out, int out_size, void* d_ws, size_t ws_size,
                              hipStream_t stream) {
    const float* x       = (const float*)d_in[0];
    const float* anchors = (const float*)d_in[1];
    const float* W1      = (const float*)d_in[2];
    const float* b1      = (const float*)d_in[3];
    const float* W2      = (const float*)d_in[4];
    const float* b2      = (const float*)d_in[5];
    float* out = (float*)d_out;

    char* ws = (char*)d_ws;
    int*   cnthist = (int*)(ws + OFF_CNTH);
    int*   offs    = (int*)(ws + OFF_OFFS);
    int*   cur     = (int*)(ws + OFF_CUR);
    int*   idxs    = (int*)(ws + OFF_IDX);
    float* gates   = (float*)(ws + OFF_GATE);
    int*   rowmap  = (int*)(ws + OFF_ROWMAP);
    float* rowgate = (float*)(ws + OFF_ROWGATE);
    u16*   Xg      = (u16*)(ws + OFF_XG);
    u16*   W1T     = (u16*)(ws + OFF_W1T);
    u16*   W2T     = (u16*)(ws + OFF_W2T);
    u16*   Hg      = (u16*)(ws + OFF_HG);

    // d_out sections (fp32 elements): out | a_n | scores | topk_idx
    float* out_main   = out;
    float* out_an     = out + (size_t)T_TOK * D_DIM;
    float* out_scores = out_an + E_EXP * D_DIM;
    float* out_idx    = out_scores + (size_t)T_TOK * E_EXP;

    pre_k<<<PRE_BLOCKS, 256, 0, stream>>>(x, anchors, W1, W1T, W2, W2T,
                                          out_main, out_an, out_scores, out_idx,
                                          idxs, gates, cnthist, Xg,
                                          rowmap, rowgate, cur);
    scatter_k<<<2048, 256, 0, stream>>>(x, cnthist, idxs, gates, cur, offs,
                                        rowmap, rowgate, Xg);
    // gemm1: 8 n-tiles(256) x 72 m-tiles(128) = 576 blocks (XCD-swizzled)
    gemm_k<0><<<8 * MAXTILES, 512, 0, stream>>>(
        Xg, D_DIM, W1T, D_DIM, Hg, b1, nullptr, nullptr,
        rowmap, nullptr, offs, D_DIM, 8);
    // gemm2: 2 n-tiles(256) x 72 m-tiles x splitK4 = 576 blocks
    gemm_k<1><<<2 * MAXTILES * 4, 512, 0, stream>>>(
        Hg, F_DIM, W2T, F_DIM, nullptr, nullptr, out_main, b2,
        rowmap, rowgate, offs, F_DIM / 4, 2);
}

// Round 8
// 304.810 us; speedup vs baseline: 1.9399x; 1.1945x over previous
//
#include <hip/hip_runtime.h>
#include <cstdint>

// ---------------------------------------------------------------------------
// Round 21. r20 post-mortem: 128x256 honestly tested = 113us/gemm (1.9 TB/s
// staged) vs r18 128^2 = 59us (4.9 TB/s). Law: drain-to-0 needs >=4
// independent 4-wave gangs/CU; regs (64 AGPR acc + ~60 VGPR) cap 16 waves/CU
// -> 4x4-wave gangs is the optimum. Tile search exhausted. This round BANKS
// the two proven halves: r18's exact gemm core (128^2, 256thr, bounds(256,4),
// 32KB single buf, drain-to-0, swizzle) + r19/r20's fused front-end
// (pre_k + scatter_k, validated correct, ~20us cheaper than r18's).
// Predict: gemm ~59 each, FETCH ~29MB, conflicts 0, total ~195-210.
// ---------------------------------------------------------------------------

#define T_TOK 4096
#define D_DIM 512
#define F_DIM 2048
#define E_EXP 8
#define NROWS 9216      // 8192 assignments + 8*128 pad
#define MAXTILES 72     // NROWS / 128

typedef __bf16 bf16x8 __attribute__((ext_vector_type(8)));
typedef float  f32x4  __attribute__((ext_vector_type(4)));
typedef unsigned short u16;
typedef unsigned short u16x8 __attribute__((ext_vector_type(8)));

__device__ __forceinline__ u16 f2b(float f) {
    return __builtin_bit_cast(unsigned short, (__bf16)f);
}
__device__ __forceinline__ void gload16(void* lds, const void* g) {
    __builtin_amdgcn_global_load_lds(
        (const __attribute__((address_space(1))) void*)g,
        (__attribute__((address_space(3))) void*)lds, 16, 0, 0);
}
// tanh-approx GELU (err ~3e-4 << bf16 ulp)
__device__ __forceinline__ float gelu_f(float v) {
    float z = 0.7978845608f * (v + 0.044715f * v * v * v);
    float t = 1.0f - 2.0f / (1.0f + __expf(2.0f * z));
    return 0.5f * v * (1.0f + t);
}

// ---------------- transpose tile body (shared by pre_k) ---------------------
__device__ __forceinline__ void tbody(const float* __restrict__ in,
                                      u16* __restrict__ out, int R, int C,
                                      int c0, int r0, int tid,
                                      float (*t)[65]) {
    int cq = tid & 15, rb = tid >> 4;
#pragma unroll
    for (int pass = 0; pass < 4; ++pass) {
        int rr = rb + pass * 16;
        float4 v = *(const float4*)(in + (size_t)(r0 + rr) * C + c0 + cq * 4);
        t[rr][cq * 4 + 0] = v.x; t[rr][cq * 4 + 1] = v.y;
        t[rr][cq * 4 + 2] = v.z; t[rr][cq * 4 + 3] = v.w;
    }
    __syncthreads();
    int rg = tid & 15, cb = tid >> 4;
#pragma unroll
    for (int pass = 0; pass < 4; ++pass) {
        int c = cb + pass * 16;
        ushort4 o;
        o.x = f2b(t[rg * 4 + 0][c]); o.y = f2b(t[rg * 4 + 1][c]);
        o.z = f2b(t[rg * 4 + 2][c]); o.w = f2b(t[rg * 4 + 3][c]);
        *(ushort4*)(out + (size_t)(c0 + c) * R + r0 + rg * 4) = o;
    }
}

// ---------------- pre_k: routing + transposes + all zero/init, ONE dispatch -
// [0,64): routing   [64,4160): W1/W2 transpose   [4160,5184): zero outm
// [5184,7488): zero Xg   [7488]: rowmap=-1, rowgate=0, cur=0
#define RT_BLKS 64
#define TR_BLKS 4096
#define ZO_BLKS 1024
#define XZ_BLKS 2304
#define PRE_BLOCKS (RT_BLKS + TR_BLKS + ZO_BLKS + XZ_BLKS + 1)

__global__ void pre_k(const float* __restrict__ x, const float* __restrict__ anchors,
                      const float* __restrict__ W1, u16* __restrict__ W1T,
                      const float* __restrict__ W2, u16* __restrict__ W2T,
                      float* __restrict__ outm, float* __restrict__ dout_an,
                      float* __restrict__ dout_scores, float* __restrict__ dout_idx,
                      int* __restrict__ idxs, float* __restrict__ gates,
                      int* __restrict__ cnthist, u16* __restrict__ Xg,
                      int* __restrict__ rowmap, float* __restrict__ rowgate,
                      int* __restrict__ cur) {
    __shared__ float shpool[E_EXP * 544];   // routing: anl; transpose: 64x65
    __shared__ int hist[E_EXP];
    int b = blockIdx.x;
    int tid = threadIdx.x;

    if (b >= RT_BLKS + TR_BLKS + ZO_BLKS + XZ_BLKS) {   // ---- misc init ----
        if (tid < E_EXP) cur[tid] = 0;
        for (int r = tid; r < NROWS; r += 256) {
            rowmap[r] = -1; rowgate[r] = 0.f;
        }
        return;
    }
    if (b >= RT_BLKS + TR_BLKS + ZO_BLKS) {             // ---- zero Xg ----
        int zb = b - (RT_BLKS + TR_BLKS + ZO_BLKS);
        float4* g4 = (float4*)Xg;
        g4[zb * 256 + tid] = float4{0.f, 0.f, 0.f, 0.f};
        return;
    }
    if (b >= RT_BLKS + TR_BLKS) {                       // ---- zero outm ----
        int zb = b - (RT_BLKS + TR_BLKS);
        float4* o4 = (float4*)outm;
        int i = zb * 256 + tid;
        o4[i] = float4{0.f, 0.f, 0.f, 0.f};
        o4[i + ZO_BLKS * 256] = float4{0.f, 0.f, 0.f, 0.f};
        return;
    }
    if (b >= RT_BLKS) {                                 // ---- transposes ----
        float (*tsh)[65] = (float(*)[65])shpool;        // 4160 floats <= 4352
        int tt = b - RT_BLKS;
        if (tt < 2048) {                    // W1 [E][512][2048] -> [E][2048][512]
            int bx = tt & 31, by = (tt >> 5) & 7, bz = tt >> 8;
            size_t zoff = (size_t)bz * D_DIM * F_DIM;
            tbody(W1 + zoff, W1T + zoff, D_DIM, F_DIM, bx * 64, by * 64, tid, tsh);
        } else {                            // W2 [E][2048][512] -> [E][512][2048]
            int t2 = tt - 2048;
            int bx = t2 & 7, by = (t2 >> 3) & 31, bz = t2 >> 8;
            size_t zoff = (size_t)bz * D_DIM * F_DIM;
            tbody(W2 + zoff, W2T + zoff, F_DIM, D_DIM, bx * 64, by * 64, tid, tsh);
        }
        return;
    }

    // ---- routing ----
    float* anl = shpool;                    // [e][p*136 + i], i<128
    if (tid < E_EXP) hist[tid] = 0;
    for (int i = tid; i < E_EXP * D_DIM; i += 256) {
        int e = i >> 9, d = i & 511;
        anl[e * 544 + (d >> 7) * 136 + (d & 127)] = anchors[i];
    }
    __syncthreads();
    {   // normalize anchors in LDS: 32 threads per anchor
        int e = tid >> 5, l = tid & 31;
        float ss = 0.f;
        for (int d = l; d < D_DIM; d += 32) {
            float v = anl[e * 544 + (d >> 7) * 136 + (d & 127)];
            ss += v * v;
        }
#pragma unroll
        for (int off = 16; off >= 1; off >>= 1) ss += __shfl_xor(ss, off, 32);
        float inv = 1.0f / fmaxf(sqrtf(ss), 1e-8f);
        for (int d = l; d < D_DIM; d += 32) {
            int ix = e * 544 + (d >> 7) * 136 + (d & 127);
            float nv = anl[ix] * inv;
            anl[ix] = nv;
            if (b == 0) dout_an[e * D_DIM + d] = nv;
        }
    }
    __syncthreads();

    int p = tid & 3;
    int tok = b * 64 + (tid >> 2);
    const float4* xr = (const float4*)(x + (size_t)tok * D_DIM + p * 128);
    const float* ab = &anl[p * 136];
    float dot[E_EXP] = {};
    float ss = 0.f;
    for (int c = 0; c < 32; ++c) {
        float4 xv = xr[c];
        ss += xv.x*xv.x + xv.y*xv.y + xv.z*xv.z + xv.w*xv.w;
#pragma unroll
        for (int e = 0; e < E_EXP; ++e) {
            float4 av = *(const float4*)&ab[e * 544 + c * 4];
            dot[e] += xv.x*av.x + xv.y*av.y + xv.z*av.z + xv.w*av.w;
        }
    }
#pragma unroll
    for (int off = 1; off <= 2; off <<= 1) {
        ss += __shfl_xor(ss, off, 64);
#pragma unroll
        for (int e = 0; e < E_EXP; ++e) dot[e] += __shfl_xor(dot[e], off, 64);
    }

    if (p == 0) {
        float inv = 1.0f / fmaxf(sqrtf(ss), 1e-8f);
        float s[E_EXP];
#pragma unroll
        for (int e = 0; e < E_EXP; ++e) s[e] = dot[e] * inv;
        int i0 = 0; float b0 = s[0];
#pragma unroll
        for (int e = 1; e < E_EXP; ++e) if (s[e] > b0) { b0 = s[e]; i0 = e; }
        int i1 = -1; float b1v = -1e30f;
#pragma unroll
        for (int e = 0; e < E_EXP; ++e)
            if (e != i0 && s[e] > b1v) { b1v = s[e]; i1 = e; }
        if (i1 < 0) { i1 = (i0 + 1) & 7; b1v = s[i1]; }   // NaN-safety
        float g0 = 1.0f / (1.0f + expf(b1v - b0));
        float g1 = 1.0f - g0;
#pragma unroll
        for (int e = 0; e < E_EXP; ++e) dout_scores[tok * E_EXP + e] = s[e];
        dout_idx[tok * 2 + 0] = (float)i0;
        dout_idx[tok * 2 + 1] = (float)i1;
        idxs[tok * 2 + 0] = i0; idxs[tok * 2 + 1] = i1;
        gates[tok * 2 + 0] = g0; gates[tok * 2 + 1] = g1;
        atomicAdd(&hist[i0], 1);
        atomicAdd(&hist[i1], 1);
    }
    __syncthreads();
    if (tid < E_EXP) cnthist[b * E_EXP + tid] = hist[tid];
}

// ---------------- scatter_k: fused assign + gather (wave per assignment) ----
// 2048 blocks x 4 waves = 8192 waves = one per (token,k) assignment.
// Each wave: atomic slot grab in expert bucket, write rowmap/rowgate, copy
// x[t] row -> Xg[r] bf16 (64 lanes x 8 elems). Block 0 publishes offs.
__global__ void scatter_k(const float* __restrict__ x, const int* __restrict__ cnthist,
                          const int* __restrict__ idxs, const float* __restrict__ gates,
                          int* __restrict__ cur, int* __restrict__ offs,
                          int* __restrict__ rowmap, float* __restrict__ rowgate,
                          u16* __restrict__ Xg) {
    __shared__ int soff[E_EXP + 1];
    __shared__ int scnt[E_EXP];
    int tid = threadIdx.x;
    if (tid < E_EXP) {
        int s = 0;
        for (int b = 0; b < RT_BLKS; ++b) s += cnthist[b * E_EXP + tid];
        scnt[tid] = s;
    }
    __syncthreads();
    if (tid == 0) {
        int acc = 0;
        for (int e = 0; e < E_EXP; ++e) { soff[e] = acc; acc += (scnt[e] + 127) & ~127; }
        soff[E_EXP] = acc;
    }
    __syncthreads();
    if (blockIdx.x == 0 && tid <= E_EXP) offs[tid] = soff[tid];

    int w = tid >> 6, lane = tid & 63;
    int p = blockIdx.x * 4 + w;          // assignment pair 0..8191
    int t = p >> 1, k = p & 1;
    int e = idxs[t * 2 + k];
    e = min(max(e, 0), E_EXP - 1);
    int r = 0;
    if (lane == 0) r = soff[e] + atomicAdd(&cur[e], 1);
    r = __shfl(r, 0, 64);
    if (lane == 0) {
        rowmap[r] = t;
        rowgate[r] = gates[t * 2 + k];
    }
    const float4* xs = (const float4*)(x + (size_t)t * D_DIM + lane * 8);
    float4 v0 = xs[0], v1 = xs[1];
    u16x8 o = { f2b(v0.x), f2b(v0.y), f2b(v0.z), f2b(v0.w),
                f2b(v1.x), f2b(v1.y), f2b(v1.z), f2b(v1.w) };
    *(u16x8*)(Xg + (size_t)r * D_DIM + lane * 8) = o;
}

// ---------------- grouped GEMM core (r21 = r18's proven core) ---------------
// MODE 0: Hg = bf16(gelu(Xg @ W1e^T + b1e))         (N=F, K=D), NT=16
// MODE 1: out[tok] += gate*(Hg @ W2e^T + [z0]b2e)   (N=D, K=F, split-K=2), NT=4
// 128x128 tile, 256 thr (4 waves, 2m x 2n, 64x64/wave), 32KB static LDS,
// drain-to-0 per K-step; 4 independent gangs/CU do the latency hiding
// (measured 4.9 TB/s staged vs 1.9-2.4 for every low-gang variant).
// XOR col swizzle kc^(row&7): global source pre-swizzled, read side XORed.
template <int MODE>
__launch_bounds__(256, 4)
__global__ void gemm_k(const u16* __restrict__ A, int lda,
                       const u16* __restrict__ BtBase, int ldb,
                       u16* __restrict__ Hout, const float* __restrict__ b1,
                       float* __restrict__ outm, const float* __restrict__ b2,
                       const int* __restrict__ rowmap, const float* __restrict__ rowgate,
                       const int* __restrict__ offs, int kPer, int nT) {
    int L = blockIdx.x;
    int per = gridDim.x >> 3;
    int tile = (L & 7) * per + (L >> 3);
    int z = 0;
    if (MODE == 1) {                 // split-K 2: high half of tiles is z=1
        int half = gridDim.x >> 1;
        z = tile >= half; tile -= z * half;
    }
    int mtile = tile / nT;
    int n0 = (tile - mtile * nT) * 128;
    int row0 = mtile * 128;
    if (row0 >= offs[E_EXP]) return;
    int e = 0;
#pragma unroll
    for (int i = 1; i < E_EXP; ++i) if (row0 >= offs[i]) e = i;
    const u16* Bt = BtBase + (size_t)e * D_DIM * F_DIM;
    int k_begin = z * kPer;
    int k_end = k_begin + kPer;

    alignas(16) __shared__ u16 As[128 * 64];
    alignas(16) __shared__ u16 Bs[128 * 64];

    int tid = threadIdx.x;
    int lane = tid & 63;
    int wv = tid >> 6;
    int wm = wv & 1, wn = wv >> 1;
    int kq = lane >> 4;          // quad 0..3
    int l15 = lane & 15;

    // staging: slot = i*256 + tid; m = slot>>3; kc = slot&7.
    // LDS dest LINEAR slot*16B; global source column pre-swizzled kc^(m&7).
    const u16* aSrc[4]; const u16* bSrc[4];
    u16* aDst[4]; u16* bDst[4];
#pragma unroll
    for (int i = 0; i < 4; ++i) {
        int slot = i * 256 + tid;
        int m = slot >> 3;
        int kc = slot & 7;
        int kcs = kc ^ (m & 7);
        aSrc[i] = A + (size_t)(row0 + m) * lda + kcs * 8;
        bSrc[i] = Bt + (size_t)(n0 + m) * ldb + kcs * 8;
        aDst[i] = As + slot * 8;
        bDst[i] = Bs + slot * 8;
    }

    f32x4 acc[4][4];
#pragma unroll
    for (int i = 0; i < 4; ++i)
#pragma unroll
        for (int j = 0; j < 4; ++j) acc[i][j] = f32x4{0.f, 0.f, 0.f, 0.f};

    int sx = l15 & 7;            // row&7 == l15&7 (wm*64, i*16 ≡ 0 mod 8)
    for (int k0 = k_begin; k0 < k_end; k0 += 64) {
#pragma unroll
        for (int i = 0; i < 4; ++i) gload16(aDst[i], aSrc[i] + k0);
#pragma unroll
        for (int i = 0; i < 4; ++i) gload16(bDst[i], bSrc[i] + k0);
        asm volatile("s_waitcnt vmcnt(0)" ::: "memory");
        __syncthreads();
#pragma unroll
        for (int kk = 0; kk < 2; ++kk) {
            int kc = kk * 4 + kq;
            int kca = kc ^ sx;   // swizzled column on the read side
            bf16x8 af[4], bfr[4];
#pragma unroll
            for (int i = 0; i < 4; ++i) {
                int rowA = wm * 64 + i * 16 + l15;
                af[i] = *(const bf16x8*)(As + rowA * 64 + kca * 8);
                int rowB = wn * 64 + i * 16 + l15;
                bfr[i] = *(const bf16x8*)(Bs + rowB * 64 + kca * 8);
            }
#pragma unroll
            for (int i = 0; i < 4; ++i)
#pragma unroll
                for (int j = 0; j < 4; ++j)
                    acc[i][j] = __builtin_amdgcn_mfma_f32_16x16x32_bf16(
                        af[i], bfr[j], acc[i][j], 0, 0, 0);
        }
        __syncthreads();
    }

    if constexpr (MODE == 0) {
        const float* b1e = b1 + (size_t)e * F_DIM;
#pragma unroll
        for (int i = 0; i < 4; ++i) {
            int gr = row0 + wm * 64 + i * 16 + kq * 4;
#pragma unroll
            for (int j = 0; j < 4; ++j) {
                int gc = n0 + wn * 64 + j * 16 + l15;
                float bb = b1e[gc];
#pragma unroll
                for (int r = 0; r < 4; ++r) {
                    float v = acc[i][j][r] + bb;
                    Hout[(size_t)(gr + r) * F_DIM + gc] = f2b(gelu_f(v));
                }
            }
        }
    } else {
        const float* b2e = b2 + (size_t)e * D_DIM;
        bool addBias = (k_begin == 0);
#pragma unroll
        for (int i = 0; i < 4; ++i) {
            int grb = row0 + wm * 64 + i * 16 + kq * 4;
#pragma unroll
            for (int r = 0; r < 4; ++r) {
                int tok = rowmap[grb + r];
                float g = rowgate[grb + r];
                if (tok >= 0 && tok < T_TOK) {
                    float* orow = outm + (size_t)tok * D_DIM;
#pragma unroll
                    for (int j = 0; j < 4; ++j) {
                        int gc = n0 + wn * 64 + j * 16 + l15;
                        float bb = addBias ? b2e[gc] : 0.f;
                        atomicAdd(orow + gc, g * (acc[i][j][r] + bb));
                    }
                }
            }
        }
    }
}

// ---------------- workspace layout (bytes) ----------------------------------
#define OFF_CNTH    0x10000u     // int[64*8] per-block histograms
#define OFF_OFFS    0x10900u     // int[9]
#define OFF_CUR     0x10A00u     // int[8] atomic cursors
#define OFF_IDX     0x20000u     // int[T*2]
#define OFF_GATE    0x28000u     // float[T*2]
#define OFF_ROWMAP  0x30000u     // int[NROWS]
#define OFF_ROWGATE 0x40000u     // float[NROWS]
#define OFF_XG      0x900000u    // 9.44 MB u16[NROWS*D]  -> ends 0x1200000
#define OFF_W1T     0x1200000u   // 16.78 MB u16[E][F][D] -> ends 0x2200000
#define OFF_W2T     0x2200000u   // 16.78 MB u16[E][D][F] -> ends 0x3200000
#define OFF_HG      0x3200000u   // 37.75 MB u16[NROWS*F] -> ends 0x5600000

extern "C" void kernel_launch(void* const* d_in, const int* in_sizes, int n_in,
                              void* d_out, int out_size, void* d_ws, size_t ws_size,
                              hipStream_t stream) {
    const float* x       = (const float*)d_in[0];
    const float* anchors = (const float*)d_in[1];
    const float* W1      = (const float*)d_in[2];
    const float* b1      = (const float*)d_in[3];
    const float* W2      = (const float*)d_in[4];
    const float* b2      = (const float*)d_in[5];
    float* out = (float*)d_out;

    char* ws = (char*)d_ws;
    int*   cnthist = (int*)(ws + OFF_CNTH);
    int*   offs    = (int*)(ws + OFF_OFFS);
    int*   cur     = (int*)(ws + OFF_CUR);
    int*   idxs    = (int*)(ws + OFF_IDX);
    float* gates   = (float*)(ws + OFF_GATE);
    int*   rowmap  = (int*)(ws + OFF_ROWMAP);
    float* rowgate = (float*)(ws + OFF_ROWGATE);
    u16*   Xg      = (u16*)(ws + OFF_XG);
    u16*   W1T     = (u16*)(ws + OFF_W1T);
    u16*   W2T     = (u16*)(ws + OFF_W2T);
    u16*   Hg      = (u16*)(ws + OFF_HG);

    // d_out sections (fp32 elements): out | a_n | scores | topk_idx
    float* out_main   = out;
    float* out_an     = out + (size_t)T_TOK * D_DIM;
    float* out_scores = out_an + E_EXP * D_DIM;
    float* out_idx    = out_scores + (size_t)T_TOK * E_EXP;

    pre_k<<<PRE_BLOCKS, 256, 0, stream>>>(x, anchors, W1, W1T, W2, W2T,
                                          out_main, out_an, out_scores, out_idx,
                                          idxs, gates, cnthist, Xg,
                                          rowmap, rowgate, cur);
    scatter_k<<<2048, 256, 0, stream>>>(x, cnthist, idxs, gates, cur, offs,
                                        rowmap, rowgate, Xg);
    // gemm1: 16 n-tiles x 72 m-tiles = 1152 blocks (1D, XCD-swizzled)
    gemm_k<0><<<16 * MAXTILES, 256, 0, stream>>>(
        Xg, D_DIM, W1T, D_DIM, Hg, b1, nullptr, nullptr,
        rowmap, nullptr, offs, D_DIM, 16);
    // gemm2: 4 n-tiles x 72 m-tiles x splitK2 = 576 blocks (1D, XCD-swizzled)
    gemm_k<1><<<4 * MAXTILES * 2, 256, 0, stream>>>(
        Hg, F_DIM, W2T, F_DIM, nullptr, nullptr, out_main, b2,
        rowmap, rowgate, offs, F_DIM / 2, 4);
}

// Round 10
// 215.451 us; speedup vs baseline: 2.7444x; 1.4148x over previous
//
#include <hip/hip_runtime.h>
#include <cstdint>

// ---------------------------------------------------------------------------
// Round 23 = r22 resubmit (r22 bench was an infra failure: "container failed
// twice", no measurement). r21 post-mortem: scatter_k = 98.7us — 8192 waves
// serialized on atomicAdd to 8 global cursors (occ 68%, VALU 1.3%, nothing
// busy = pure RMW serialization). Fix: DETERMINISTIC slot assignment, zero
// atomics in scatter:
//   - pre_k routing stores the LDS-hist atomicAdd return = within-block
//     rank per assignment (ranks[t*2+k]).
//   - scatter_k: slot = soff[e] + waveReduce(cnthist[l][e], l<rb) + rank.
//   - drop Xg zeroing (pad Hg rows are discarded by rowmap<0 in gemm2;
//     MFMA row m depends only on A row m, so garbage pad rows are inert).
// gemm cores untouched (r18's proven 128^2 4-gang core, 59us each).
// Predict: scatter 98.7 -> ~10us, pre_k slightly faster, gemms ~59 each,
// total 304.8 -> ~195-210 (new best).
// ---------------------------------------------------------------------------

#define T_TOK 4096
#define D_DIM 512
#define F_DIM 2048
#define E_EXP 8
#define NROWS 9216      // 8192 assignments + 8*128 pad
#define MAXTILES 72     // NROWS / 128

typedef __bf16 bf16x8 __attribute__((ext_vector_type(8)));
typedef float  f32x4  __attribute__((ext_vector_type(4)));
typedef unsigned short u16;
typedef unsigned short u16x8 __attribute__((ext_vector_type(8)));

__device__ __forceinline__ u16 f2b(float f) {
    return __builtin_bit_cast(unsigned short, (__bf16)f);
}
__device__ __forceinline__ void gload16(void* lds, const void* g) {
    __builtin_amdgcn_global_load_lds(
        (const __attribute__((address_space(1))) void*)g,
        (__attribute__((address_space(3))) void*)lds, 16, 0, 0);
}
// tanh-approx GELU (err ~3e-4 << bf16 ulp)
__device__ __forceinline__ float gelu_f(float v) {
    float z = 0.7978845608f * (v + 0.044715f * v * v * v);
    float t = 1.0f - 2.0f / (1.0f + __expf(2.0f * z));
    return 0.5f * v * (1.0f + t);
}

// ---------------- transpose tile body (shared by pre_k) ---------------------
__device__ __forceinline__ void tbody(const float* __restrict__ in,
                                      u16* __restrict__ out, int R, int C,
                                      int c0, int r0, int tid,
                                      float (*t)[65]) {
    int cq = tid & 15, rb = tid >> 4;
#pragma unroll
    for (int pass = 0; pass < 4; ++pass) {
        int rr = rb + pass * 16;
        float4 v = *(const float4*)(in + (size_t)(r0 + rr) * C + c0 + cq * 4);
        t[rr][cq * 4 + 0] = v.x; t[rr][cq * 4 + 1] = v.y;
        t[rr][cq * 4 + 2] = v.z; t[rr][cq * 4 + 3] = v.w;
    }
    __syncthreads();
    int rg = tid & 15, cb = tid >> 4;
#pragma unroll
    for (int pass = 0; pass < 4; ++pass) {
        int c = cb + pass * 16;
        ushort4 o;
        o.x = f2b(t[rg * 4 + 0][c]); o.y = f2b(t[rg * 4 + 1][c]);
        o.z = f2b(t[rg * 4 + 2][c]); o.w = f2b(t[rg * 4 + 3][c]);
        *(ushort4*)(out + (size_t)(c0 + c) * R + r0 + rg * 4) = o;
    }
}

// ---------------- pre_k: routing + transposes + zero/init, ONE dispatch -----
// [0,64): routing (+ per-assignment ranks)  [64,4160): W1/W2 transpose
// [4160,5184): zero outm   [5184]: rowmap=-1, rowgate=0
#define RT_BLKS 64
#define TR_BLKS 4096
#define ZO_BLKS 1024
#define PRE_BLOCKS (RT_BLKS + TR_BLKS + ZO_BLKS + 1)

__global__ void pre_k(const float* __restrict__ x, const float* __restrict__ anchors,
                      const float* __restrict__ W1, u16* __restrict__ W1T,
                      const float* __restrict__ W2, u16* __restrict__ W2T,
                      float* __restrict__ outm, float* __restrict__ dout_an,
                      float* __restrict__ dout_scores, float* __restrict__ dout_idx,
                      int* __restrict__ idxs, float* __restrict__ gates,
                      int* __restrict__ cnthist, int* __restrict__ ranks,
                      int* __restrict__ rowmap, float* __restrict__ rowgate) {
    __shared__ float shpool[E_EXP * 544];   // routing: anl; transpose: 64x65
    __shared__ int hist[E_EXP];
    int b = blockIdx.x;
    int tid = threadIdx.x;

    if (b >= RT_BLKS + TR_BLKS + ZO_BLKS) {             // ---- misc init ----
        for (int r = tid; r < NROWS; r += 256) {
            rowmap[r] = -1; rowgate[r] = 0.f;
        }
        return;
    }
    if (b >= RT_BLKS + TR_BLKS) {                       // ---- zero outm ----
        int zb = b - (RT_BLKS + TR_BLKS);
        float4* o4 = (float4*)outm;
        int i = zb * 256 + tid;
        o4[i] = float4{0.f, 0.f, 0.f, 0.f};
        o4[i + ZO_BLKS * 256] = float4{0.f, 0.f, 0.f, 0.f};
        return;
    }
    if (b >= RT_BLKS) {                                 // ---- transposes ----
        float (*tsh)[65] = (float(*)[65])shpool;        // 4160 floats <= 4352
        int tt = b - RT_BLKS;
        if (tt < 2048) {                    // W1 [E][512][2048] -> [E][2048][512]
            int bx = tt & 31, by = (tt >> 5) & 7, bz = tt >> 8;
            size_t zoff = (size_t)bz * D_DIM * F_DIM;
            tbody(W1 + zoff, W1T + zoff, D_DIM, F_DIM, bx * 64, by * 64, tid, tsh);
        } else {                            // W2 [E][2048][512] -> [E][512][2048]
            int t2 = tt - 2048;
            int bx = t2 & 7, by = (t2 >> 3) & 31, bz = t2 >> 8;
            size_t zoff = (size_t)bz * D_DIM * F_DIM;
            tbody(W2 + zoff, W2T + zoff, F_DIM, D_DIM, bx * 64, by * 64, tid, tsh);
        }
        return;
    }

    // ---- routing ----
    float* anl = shpool;                    // [e][p*136 + i], i<128
    if (tid < E_EXP) hist[tid] = 0;
    for (int i = tid; i < E_EXP * D_DIM; i += 256) {
        int e = i >> 9, d = i & 511;
        anl[e * 544 + (d >> 7) * 136 + (d & 127)] = anchors[i];
    }
    __syncthreads();
    {   // normalize anchors in LDS: 32 threads per anchor
        int e = tid >> 5, l = tid & 31;
        float ss = 0.f;
        for (int d = l; d < D_DIM; d += 32) {
            float v = anl[e * 544 + (d >> 7) * 136 + (d & 127)];
            ss += v * v;
        }
#pragma unroll
        for (int off = 16; off >= 1; off >>= 1) ss += __shfl_xor(ss, off, 32);
        float inv = 1.0f / fmaxf(sqrtf(ss), 1e-8f);
        for (int d = l; d < D_DIM; d += 32) {
            int ix = e * 544 + (d >> 7) * 136 + (d & 127);
            float nv = anl[ix] * inv;
            anl[ix] = nv;
            if (b == 0) dout_an[e * D_DIM + d] = nv;
        }
    }
    __syncthreads();

    int p = tid & 3;
    int tok = b * 64 + (tid >> 2);
    const float4* xr = (const float4*)(x + (size_t)tok * D_DIM + p * 128);
    const float* ab = &anl[p * 136];
    float dot[E_EXP] = {};
    float ss = 0.f;
    for (int c = 0; c < 32; ++c) {
        float4 xv = xr[c];
        ss += xv.x*xv.x + xv.y*xv.y + xv.z*xv.z + xv.w*xv.w;
#pragma unroll
        for (int e = 0; e < E_EXP; ++e) {
            float4 av = *(const float4*)&ab[e * 544 + c * 4];
            dot[e] += xv.x*av.x + xv.y*av.y + xv.z*av.z + xv.w*av.w;
        }
    }
#pragma unroll
    for (int off = 1; off <= 2; off <<= 1) {
        ss += __shfl_xor(ss, off, 64);
#pragma unroll
        for (int e = 0; e < E_EXP; ++e) dot[e] += __shfl_xor(dot[e], off, 64);
    }

    if (p == 0) {
        float inv = 1.0f / fmaxf(sqrtf(ss), 1e-8f);
        float s[E_EXP];
#pragma unroll
        for (int e = 0; e < E_EXP; ++e) s[e] = dot[e] * inv;
        int i0 = 0; float b0 = s[0];
#pragma unroll
        for (int e = 1; e < E_EXP; ++e) if (s[e] > b0) { b0 = s[e]; i0 = e; }
        int i1 = -1; float b1v = -1e30f;
#pragma unroll
        for (int e = 0; e < E_EXP; ++e)
            if (e != i0 && s[e] > b1v) { b1v = s[e]; i1 = e; }
        if (i1 < 0) { i1 = (i0 + 1) & 7; b1v = s[i1]; }   // NaN-safety
        float g0 = 1.0f / (1.0f + expf(b1v - b0));
        float g1 = 1.0f - g0;
#pragma unroll
        for (int e = 0; e < E_EXP; ++e) dout_scores[tok * E_EXP + e] = s[e];
        dout_idx[tok * 2 + 0] = (float)i0;
        dout_idx[tok * 2 + 1] = (float)i1;
        idxs[tok * 2 + 0] = i0; idxs[tok * 2 + 1] = i1;
        gates[tok * 2 + 0] = g0; gates[tok * 2 + 1] = g1;
        // LDS-hist atomic return value = free within-block rank per expert
        int r0 = atomicAdd(&hist[i0], 1);
        int r1 = atomicAdd(&hist[i1], 1);
        ranks[tok * 2 + 0] = r0;
        ranks[tok * 2 + 1] = r1;
    }
    __syncthreads();
    if (tid < E_EXP) cnthist[b * E_EXP + tid] = hist[tid];
}

// ---------------- scatter_k: ATOMIC-FREE assign + gather --------------------
// 2048 blocks x 4 waves = 8192 waves = one per (token,k) assignment.
// slot = soff[e] + Sum_{rb'<rb} cnthist[rb'][e] (64-lane wave reduce) + rank.
// Then copy x[t] row -> Xg[slot] bf16. Block 0 publishes offs.
__global__ void scatter_k(const float* __restrict__ x, const int* __restrict__ cnthist,
                          const int* __restrict__ idxs, const int* __restrict__ ranks,
                          const float* __restrict__ gates, int* __restrict__ offs,
                          int* __restrict__ rowmap, float* __restrict__ rowgate,
                          u16* __restrict__ Xg) {
    __shared__ int soff[E_EXP + 1];
    __shared__ int scnt[E_EXP];
    int tid = threadIdx.x;
    if (tid < E_EXP) {
        int s = 0;
        for (int b = 0; b < RT_BLKS; ++b) s += cnthist[b * E_EXP + tid];
        scnt[tid] = s;
    }
    __syncthreads();
    if (tid == 0) {
        int acc = 0;
        for (int e = 0; e < E_EXP; ++e) { soff[e] = acc; acc += (scnt[e] + 127) & ~127; }
        soff[E_EXP] = acc;
    }
    __syncthreads();
    if (blockIdx.x == 0 && tid <= E_EXP) offs[tid] = soff[tid];

    int w = tid >> 6, lane = tid & 63;
    int p = blockIdx.x * 4 + w;          // assignment 0..8191
    int t = p >> 1, k = p & 1;
    int e = idxs[t * 2 + k];
    e = min(max(e, 0), E_EXP - 1);
    int rb = t >> 6;                     // routing block of token t
    // exclusive cross-block prefix for expert e: lanes < rb contribute
    int v = (lane < rb) ? cnthist[lane * E_EXP + e] : 0;
#pragma unroll
    for (int off = 32; off >= 1; off >>= 1) v += __shfl_xor(v, off, 64);
    int r = soff[e] + v + ranks[t * 2 + k];
    if (lane == 0) {
        rowmap[r] = t;
        rowgate[r] = gates[t * 2 + k];
    }
    const float4* xs = (const float4*)(x + (size_t)t * D_DIM + lane * 8);
    float4 v0 = xs[0], v1 = xs[1];
    u16x8 o = { f2b(v0.x), f2b(v0.y), f2b(v0.z), f2b(v0.w),
                f2b(v1.x), f2b(v1.y), f2b(v1.z), f2b(v1.w) };
    *(u16x8*)(Xg + (size_t)r * D_DIM + lane * 8) = o;
}

// ---------------- grouped GEMM core (r18's proven core, untouched) ----------
// MODE 0: Hg = bf16(gelu(Xg @ W1e^T + b1e))         (N=F, K=D), NT=16
// MODE 1: out[tok] += gate*(Hg @ W2e^T + [z0]b2e)   (N=D, K=F, split-K=2), NT=4
// 128x128 tile, 256 thr (4 waves, 2m x 2n, 64x64/wave), 32KB static LDS,
// drain-to-0 per K-step; 4 independent gangs/CU do the latency hiding
// (measured 4.9 TB/s staged vs 1.9-2.4 for every low-gang variant).
// XOR col swizzle kc^(row&7): global source pre-swizzled, read side XORed.
template <int MODE>
__launch_bounds__(256, 4)
__global__ void gemm_k(const u16* __restrict__ A, int lda,
                       const u16* __restrict__ BtBase, int ldb,
                       u16* __restrict__ Hout, const float* __restrict__ b1,
                       float* __restrict__ outm, const float* __restrict__ b2,
                       const int* __restrict__ rowmap, const float* __restrict__ rowgate,
                       const int* __restrict__ offs, int kPer, int nT) {
    int L = blockIdx.x;
    int per = gridDim.x >> 3;
    int tile = (L & 7) * per + (L >> 3);
    int z = 0;
    if (MODE == 1) {                 // split-K 2: high half of tiles is z=1
        int half = gridDim.x >> 1;
        z = tile >= half; tile -= z * half;
    }
    int mtile = tile / nT;
    int n0 = (tile - mtile * nT) * 128;
    int row0 = mtile * 128;
    if (row0 >= offs[E_EXP]) return;
    int e = 0;
#pragma unroll
    for (int i = 1; i < E_EXP; ++i) if (row0 >= offs[i]) e = i;
    const u16* Bt = BtBase + (size_t)e * D_DIM * F_DIM;
    int k_begin = z * kPer;
    int k_end = k_begin + kPer;

    alignas(16) __shared__ u16 As[128 * 64];
    alignas(16) __shared__ u16 Bs[128 * 64];

    int tid = threadIdx.x;
    int lane = tid & 63;
    int wv = tid >> 6;
    int wm = wv & 1, wn = wv >> 1;
    int kq = lane >> 4;          // quad 0..3
    int l15 = lane & 15;

    // staging: slot = i*256 + tid; m = slot>>3; kc = slot&7.
    // LDS dest LINEAR slot*16B; global source column pre-swizzled kc^(m&7).
    const u16* aSrc[4]; const u16* bSrc[4];
    u16* aDst[4]; u16* bDst[4];
#pragma unroll
    for (int i = 0; i < 4; ++i) {
        int slot = i * 256 + tid;
        int m = slot >> 3;
        int kc = slot & 7;
        int kcs = kc ^ (m & 7);
        aSrc[i] = A + (size_t)(row0 + m) * lda + kcs * 8;
        bSrc[i] = Bt + (size_t)(n0 + m) * ldb + kcs * 8;
        aDst[i] = As + slot * 8;
        bDst[i] = Bs + slot * 8;
    }

    f32x4 acc[4][4];
#pragma unroll
    for (int i = 0; i < 4; ++i)
#pragma unroll
        for (int j = 0; j < 4; ++j) acc[i][j] = f32x4{0.f, 0.f, 0.f, 0.f};

    int sx = l15 & 7;            // row&7 == l15&7 (wm*64, i*16 ≡ 0 mod 8)
    for (int k0 = k_begin; k0 < k_end; k0 += 64) {
#pragma unroll
        for (int i = 0; i < 4; ++i) gload16(aDst[i], aSrc[i] + k0);
#pragma unroll
        for (int i = 0; i < 4; ++i) gload16(bDst[i], bSrc[i] + k0);
        asm volatile("s_waitcnt vmcnt(0)" ::: "memory");
        __syncthreads();
#pragma unroll
        for (int kk = 0; kk < 2; ++kk) {
            int kc = kk * 4 + kq;
            int kca = kc ^ sx;   // swizzled column on the read side
            bf16x8 af[4], bfr[4];
#pragma unroll
            for (int i = 0; i < 4; ++i) {
                int rowA = wm * 64 + i * 16 + l15;
                af[i] = *(const bf16x8*)(As + rowA * 64 + kca * 8);
                int rowB = wn * 64 + i * 16 + l15;
                bfr[i] = *(const bf16x8*)(Bs + rowB * 64 + kca * 8);
            }
#pragma unroll
            for (int i = 0; i < 4; ++i)
#pragma unroll
                for (int j = 0; j < 4; ++j)
                    acc[i][j] = __builtin_amdgcn_mfma_f32_16x16x32_bf16(
                        af[i], bfr[j], acc[i][j], 0, 0, 0);
        }
        __syncthreads();
    }

    if constexpr (MODE == 0) {
        const float* b1e = b1 + (size_t)e * F_DIM;
#pragma unroll
        for (int i = 0; i < 4; ++i) {
            int gr = row0 + wm * 64 + i * 16 + kq * 4;
#pragma unroll
            for (int j = 0; j < 4; ++j) {
                int gc = n0 + wn * 64 + j * 16 + l15;
                float bb = b1e[gc];
#pragma unroll
                for (int r = 0; r < 4; ++r) {
                    float v = acc[i][j][r] + bb;
                    Hout[(size_t)(gr + r) * F_DIM + gc] = f2b(gelu_f(v));
                }
            }
        }
    } else {
        const float* b2e = b2 + (size_t)e * D_DIM;
        bool addBias = (k_begin == 0);
#pragma unroll
        for (int i = 0; i < 4; ++i) {
            int grb = row0 + wm * 64 + i * 16 + kq * 4;
#pragma unroll
            for (int r = 0; r < 4; ++r) {
                int tok = rowmap[grb + r];
                float g = rowgate[grb + r];
                if (tok >= 0 && tok < T_TOK) {
                    float* orow = outm + (size_t)tok * D_DIM;
#pragma unroll
                    for (int j = 0; j < 4; ++j) {
                        int gc = n0 + wn * 64 + j * 16 + l15;
                        float bb = addBias ? b2e[gc] : 0.f;
                        atomicAdd(orow + gc, g * (acc[i][j][r] + bb));
                    }
                }
            }
        }
    }
}

// ---------------- workspace layout (bytes) ----------------------------------
#define OFF_CNTH    0x10000u     // int[64*8] per-block histograms
#define OFF_OFFS    0x10900u     // int[9]
#define OFF_IDX     0x20000u     // int[T*2]
#define OFF_GATE    0x28000u     // float[T*2]
#define OFF_ROWMAP  0x30000u     // int[NROWS]
#define OFF_ROWGATE 0x40000u     // float[NROWS]
#define OFF_RANK    0x50000u     // int[T*2] within-block ranks
#define OFF_XG      0x900000u    // 9.44 MB u16[NROWS*D]  -> ends 0x1200000
#define OFF_W1T     0x1200000u   // 16.78 MB u16[E][F][D] -> ends 0x2200000
#define OFF_W2T     0x2200000u   // 16.78 MB u16[E][D][F] -> ends 0x3200000
#define OFF_HG      0x3200000u   // 37.75 MB u16[NROWS*F] -> ends 0x5600000

extern "C" void kernel_launch(void* const* d_in, const int* in_sizes, int n_in,
                              void* d_out, int out_size, void* d_ws, size_t ws_size,
                              hipStream_t stream) {
    const float* x       = (const float*)d_in[0];
    const float* anchors = (const float*)d_in[1];
    const float* W1      = (const float*)d_in[2];
    const float* b1      = (const float*)d_in[3];
    const float* W2      = (const float*)d_in[4];
    const float* b2      = (const float*)d_in[5];
    float* out = (float*)d_out;

    char* ws = (char*)d_ws;
    int*   cnthist = (int*)(ws + OFF_CNTH);
    int*   offs    = (int*)(ws + OFF_OFFS);
    int*   idxs    = (int*)(ws + OFF_IDX);
    float* gates   = (float*)(ws + OFF_GATE);
    int*   rowmap  = (int*)(ws + OFF_ROWMAP);
    float* rowgate = (float*)(ws + OFF_ROWGATE);
    int*   ranks   = (int*)(ws + OFF_RANK);
    u16*   Xg      = (u16*)(ws + OFF_XG);
    u16*   W1T     = (u16*)(ws + OFF_W1T);
    u16*   W2T     = (u16*)(ws + OFF_W2T);
    u16*   Hg      = (u16*)(ws + OFF_HG);

    // d_out sections (fp32 elements): out | a_n | scores | topk_idx
    float* out_main   = out;
    float* out_an     = out + (size_t)T_TOK * D_DIM;
    float* out_scores = out_an + E_EXP * D_DIM;
    float* out_idx    = out_scores + (size_t)T_TOK * E_EXP;

    pre_k<<<PRE_BLOCKS, 256, 0, stream>>>(x, anchors, W1, W1T, W2, W2T,
                                          out_main, out_an, out_scores, out_idx,
                                          idxs, gates, cnthist, ranks,
                                          rowmap, rowgate);
    scatter_k<<<2048, 256, 0, stream>>>(x, cnthist, idxs, ranks, gates, offs,
                                        rowmap, rowgate, Xg);
    // gemm1: 16 n-tiles x 72 m-tiles = 1152 blocks (1D, XCD-swizzled)
    gemm_k<0><<<16 * MAXTILES, 256, 0, stream>>>(
        Xg, D_DIM, W1T, D_DIM, Hg, b1, nullptr, nullptr,
        rowmap, nullptr, offs, D_DIM, 16);
    // gemm2: 4 n-tiles x 72 m-tiles x splitK2 = 576 blocks (1D, XCD-swizzled)
    gemm_k<1><<<4 * MAXTILES * 2, 256, 0, stream>>>(
        Hg, F_DIM, W2T, F_DIM, nullptr, nullptr, out_main, b2,
        rowmap, rowgate, offs, F_DIM / 2, 4);
}